// Round 8
// baseline (247.729 us; speedup 1.0000x reference)
//
#include <hip/hip_runtime.h>
#include <hip/hip_bf16.h>

#define N_NODES 8192
#define E_EDGES 262144
#define R_REL   2
#define F_FEAT  111
#define D_EMB   32
#define H_HID   256
#define C_CLS   15
#define HCAP    (1 << 19)          // hash capacity per relation (2MB each)

// ---------------- K1: fused prep: embed | dst-count + hash-dedup + src-count | W96 ----------------
// blocks [0,1024): X0 = x_note @ W_embed + b
// blocks [1024,3072): per-edge: dst-degree count; hash CAS dedup -> flags64 + src-degree
// blocks [3072,3168): W96 = [Ws0+Ws1; Wn0; Wn1]
__global__ void k_prep(const float* __restrict__ x_note, const float* __restrict__ W,
                       const float* __restrict__ b, float* __restrict__ X0,
                       const int* __restrict__ edges, int* __restrict__ deg,
                       unsigned int* __restrict__ hash, unsigned long long* __restrict__ flags64,
                       const float* __restrict__ Wself, const float* __restrict__ Wneigh,
                       float* __restrict__ W96) {
    int blk = blockIdx.x;
    if (blk < 1024) {
        __shared__ float Ws[F_FEAT * D_EMB];
        for (int i = threadIdx.x; i < F_FEAT * D_EMB; i += blockDim.x) Ws[i] = W[i];
        __syncthreads();
        int tid = blk * 256 + threadIdx.x;
        int n = tid >> 5, d = tid & 31;
        const float* xr = x_note + n * F_FEAT;
        float acc = b[d];
        for (int f = 0; f < F_FEAT; ++f) acc += xr[f] * Ws[f * D_EMB + d];
        X0[n * D_EMB + d] = acc;
    } else if (blk < 3072) {
        int i = (blk - 1024) * 256 + threadIdx.x;     // R*E edges
        int r = i >> 18, e = i & (E_EDGES - 1);
        int src = edges[(r * 2) * E_EDGES + e];
        int dst = edges[(r * 2 + 1) * E_EDGES + e];
        atomicAdd(&deg[(2 + r) * N_NODES + dst], 1);
        unsigned int key = (((unsigned int)src << 13) | (unsigned int)dst) + 1u;  // nonzero
        unsigned int* tab = hash + r * HCAP;
        unsigned int slot = (key * 2654435761u) >> 13;   // top 19 bits
        slot &= (HCAP - 1);
        bool first = false;
        for (;;) {
            unsigned int prev = atomicCAS(&tab[slot], 0u, key);
            if (prev == 0u) { first = true; break; }
            if (prev == key) break;
            slot = (slot + 1) & (HCAP - 1);
        }
        unsigned long long bal = __ballot(first);
        if ((threadIdx.x & 63) == 0) flags64[i >> 6] = bal;
        if (first) atomicAdd(&deg[r * N_NODES + src], 1);
    } else {
        int i = (blk - 3072) * 256 + threadIdx.x;     // 96*256
        int dd = i >> 8, h = i & 255;
        float v;
        if (dd < 32)      v = Wself[dd * 256 + h] + Wself[(32 + dd) * 256 + h];
        else if (dd < 64) v = Wneigh[(dd - 32) * 256 + h];
        else              v = Wneigh[(32 + dd - 64) * 256 + h];
        W96[i] = v;
    }
}

// ---------------- K2: exclusive scan of deg -> rowptr (one block per array, 4 arrays) ----------------
__global__ void k_scan(const int* __restrict__ deg, int* __restrict__ rowptr) {
    int r = blockIdx.x;
    __shared__ int part[1024];
    int t = threadIdx.x;
    int base = t * 8;
    int local[8];
    int s = 0;
    #pragma unroll
    for (int i = 0; i < 8; ++i) { local[i] = s; s += deg[r * N_NODES + base + i]; }
    part[t] = s;
    __syncthreads();
    for (int off = 1; off < 1024; off <<= 1) {
        int v = (t >= off) ? part[t - off] : 0;
        __syncthreads();
        if (t >= off) part[t] += v;
        __syncthreads();
    }
    int pre = (t > 0) ? part[t - 1] : 0;
    #pragma unroll
    for (int i = 0; i < 8; ++i) rowptr[r * (N_NODES + 1) + base + i] = pre + local[i];
    if (t == 1023) rowptr[r * (N_NODES + 1) + N_NODES] = part[1023];
}

// ---------------- K3: fused CSR scatters: [0,2048) colD (dup, by dst) | [2048,4096) colS (dedup, by src) ----------------
// cur layout: [0,1]=src cursors, [2,3]=dst cursors
__global__ void k_build(const int* __restrict__ edges, const int* __restrict__ rowptr,
                        const unsigned long long* __restrict__ flags64,
                        int* __restrict__ cur, int* __restrict__ colD, int* __restrict__ colS) {
    int blk = blockIdx.x;
    if (blk < 2048) {
        int i = blk * 256 + threadIdx.x;               // R*E edges
        int r = i >> 18, e = i & (E_EDGES - 1);
        int src = edges[(r * 2) * E_EDGES + e];
        int dst = edges[(r * 2 + 1) * E_EDGES + e];
        int posD = rowptr[(2 + r) * (N_NODES + 1) + dst] + atomicAdd(&cur[(2 + r) * N_NODES + dst], 1);
        colD[r * E_EDGES + posD] = src;
    } else {
        int i = (blk - 2048) * 256 + threadIdx.x;      // R*E edges
        if (!((flags64[i >> 6] >> (i & 63)) & 1ull)) return;
        int r = i >> 18, e = i & (E_EDGES - 1);
        int src = edges[(r * 2) * E_EDGES + e];
        int dst = edges[(r * 2 + 1) * E_EDGES + e];
        int posS = rowptr[r * (N_NODES + 1) + src] + atomicAdd(&cur[r * N_NODES + src], 1);
        colS[r * E_EDGES + posS] = dst;
    }
}

// ---------------- K4: xin[n] = [X0[n] | mean_r0 | mean_r1]  (gather, unroll-4) ----------------
__global__ __launch_bounds__(256) void k_mean(const float* __restrict__ X0,
                                              const int* __restrict__ rowptr,
                                              const int* __restrict__ colD,
                                              float* __restrict__ xin) {
    int p = blockIdx.x * 8 + (threadIdx.x >> 5);   // (node, relation) pair, 16384 total
    int d = threadIdx.x & 31;
    int n = p >> 1, r = p & 1;
    int s  = rowptr[(2 + r) * (N_NODES + 1) + n];
    int e2 = rowptr[(2 + r) * (N_NODES + 1) + n + 1];
    const int* cr = colD + r * E_EDGES;
    float a0 = 0.f, a1 = 0.f, a2 = 0.f, a3 = 0.f;
    int idx = s;
    for (; idx + 4 <= e2; idx += 4) {
        int c0 = cr[idx], c1 = cr[idx + 1], c2 = cr[idx + 2], c3 = cr[idx + 3];
        a0 += X0[c0 * D_EMB + d]; a1 += X0[c1 * D_EMB + d];
        a2 += X0[c2 * D_EMB + d]; a3 += X0[c3 * D_EMB + d];
    }
    for (; idx < e2; ++idx) a0 += X0[cr[idx] * D_EMB + d];
    float inv = 1.f / fmaxf((float)(e2 - s), 1.f);
    xin[n * 96 + 32 + r * 32 + d] = ((a0 + a1) + (a2 + a3)) * inv;
    if (r == 0) xin[n * 96 + d] = X0[n * D_EMB + d];
}

// ---------------- K5: H1 = relu(xin @ W96 + b) — tiled GEMM 64x64x96 ----------------
__global__ __launch_bounds__(256) void k_gemm96(const float* __restrict__ xin,
                                                const float* __restrict__ W96,
                                                const float* __restrict__ bg,
                                                float* __restrict__ H1) {
    __shared__ float As[64][97];   // pad -> bank-conflict-free column reads
    __shared__ float Bs[96][64];
    int bm = blockIdx.x >> 2, bn = blockIdx.x & 3;
    int t = threadIdx.x;
    int nb = bm * 64, cb = bn * 64;
    for (int i = t; i < 64 * 96; i += 256) { int row = i / 96, k = i - row * 96; As[row][k] = xin[(nb + row) * 96 + k]; }
    for (int i = t; i < 96 * 64; i += 256) { int k = i >> 6, col = i & 63; Bs[k][col] = W96[k * 256 + cb + col]; }
    __syncthreads();
    int tx = t & 15, ty = t >> 4;
    float acc[4][4] = {};
    #pragma unroll 4
    for (int k = 0; k < 96; ++k) {
        float a0 = As[ty * 4 + 0][k], a1 = As[ty * 4 + 1][k], a2 = As[ty * 4 + 2][k], a3 = As[ty * 4 + 3][k];
        float b0 = Bs[k][tx * 4 + 0], b1 = Bs[k][tx * 4 + 1], b2 = Bs[k][tx * 4 + 2], b3 = Bs[k][tx * 4 + 3];
        acc[0][0] += a0 * b0; acc[0][1] += a0 * b1; acc[0][2] += a0 * b2; acc[0][3] += a0 * b3;
        acc[1][0] += a1 * b0; acc[1][1] += a1 * b1; acc[1][2] += a1 * b2; acc[1][3] += a1 * b3;
        acc[2][0] += a2 * b0; acc[2][1] += a2 * b1; acc[2][2] += a2 * b2; acc[2][3] += a2 * b3;
        acc[3][0] += a3 * b0; acc[3][1] += a3 * b1; acc[3][2] += a3 * b2; acc[3][3] += a3 * b3;
    }
    #pragma unroll
    for (int i = 0; i < 4; ++i) {
        int n = nb + ty * 4 + i;
        #pragma unroll
        for (int j = 0; j < 4; ++j) {
            int c = cb + tx * 4 + j;
            H1[n * H_HID + c] = fmaxf(acc[i][j] + bg[c] + bg[H_HID + c], 0.f);
        }
    }
}

// ---------------- K6: G1 = H1 @ W_s1 (pad col 15 with 0), LDS-staged ----------------
__global__ __launch_bounds__(256) void k_g1(const float* __restrict__ H1,
                                            const float* __restrict__ Ws,
                                            float* __restrict__ G1) {
    __shared__ float hl[16][H_HID + 1];
    __shared__ float Wlds[H_HID][16];
    int t = threadIdx.x;
    int nb = blockIdx.x * 16;
    #pragma unroll
    for (int c = 0; c < C_CLS; ++c) Wlds[t][c] = Ws[t * C_CLS + c];
    #pragma unroll
    for (int i = 0; i < 16; ++i) hl[i][t] = H1[(nb + i) * H_HID + t];
    __syncthreads();
    int g = t >> 4, c = t & 15;
    float acc = 0.f;
    if (c < C_CLS) {
        #pragma unroll 4
        for (int h = 0; h < H_HID; ++h) acc += hl[g][h] * Wlds[h][c];
    }
    G1[(nb + g) * 16 + c] = acc;   // c==15 lane writes 0
}

// ---------------- K7: logits[n] = sum_{j in N(n)} G1[j]; S1 = softmax; also S1p (stride-16) ----------------
__global__ __launch_bounds__(256) void k_logits_sm(const int* __restrict__ rowptr,
                                                   const int* __restrict__ colS,
                                                   const float* __restrict__ G1,
                                                   float* __restrict__ S1,
                                                   float* __restrict__ S1p) {
    int n = (blockIdx.x * blockDim.x + threadIdx.x) >> 4;   // node
    int c = threadIdx.x & 15;
    float a0 = 0.f, a1 = 0.f, a2 = 0.f, a3 = 0.f;
    for (int r = 0; r < R_REL; ++r) {
        int s  = rowptr[r * (N_NODES + 1) + n];
        int e2 = rowptr[r * (N_NODES + 1) + n + 1];
        const int* cr = colS + r * E_EDGES;
        int idx = s;
        for (; idx + 4 <= e2; idx += 4) {
            int c0 = cr[idx + 0], c1 = cr[idx + 1], c2 = cr[idx + 2], c3 = cr[idx + 3];
            a0 += G1[c0 * 16 + c]; a1 += G1[c1 * 16 + c];
            a2 += G1[c2 * 16 + c]; a3 += G1[c3 * 16 + c];
        }
        for (; idx < e2; ++idx) a0 += G1[cr[idx] * 16 + c];
    }
    float logit = (c < C_CLS) ? ((a0 + a1) + (a2 + a3)) : -1e30f;
    float m = logit;
    for (int off = 8; off; off >>= 1) m = fmaxf(m, __shfl_xor(m, off, 16));
    float e = (c < C_CLS) ? expf(logit - m) : 0.f;
    float ssum = e;
    for (int off = 8; off; off >>= 1) ssum += __shfl_xor(ssum, off, 16);
    float p = e / ssum;
    if (c < C_CLS) S1[n * C_CLS + c] = p;
    S1p[n * 16 + c] = (c < C_CLS) ? p : 0.f;
}

// ---------------- K8: fused xp (blocks 0..31, 256 nodes each) | Tsum (blocks 32..543) ----------------
__global__ __launch_bounds__(256) void k_xpT(const float* __restrict__ S1, const float* __restrict__ H1,
                                             float* __restrict__ xp,
                                             const int* __restrict__ rowptr, const int* __restrict__ colS,
                                             const float* __restrict__ S1p, float* __restrict__ T) {
    int blk = blockIdx.x;
    if (blk < 32) {
        int h = threadIdx.x;
        int base = blk * 256;
        float acc[C_CLS];
        #pragma unroll
        for (int c = 0; c < C_CLS; ++c) acc[c] = 0.f;
        for (int i = 0; i < 256; ++i) {
            int n = base + i;
            float hv = H1[n * H_HID + h];
            const float* sr = S1 + n * C_CLS;
            #pragma unroll
            for (int c = 0; c < C_CLS; ++c) acc[c] += sr[c] * hv;
        }
        #pragma unroll
        for (int c = 0; c < C_CLS; ++c) atomicAdd(&xp[c * H_HID + h], acc[c]);
    } else {
        int grp = ((blk - 32) * 256 + threadIdx.x) >> 4;   // node
        int c = threadIdx.x & 15;
        if (c >= C_CLS) return;
        float a0 = 0.f, a1 = 0.f, a2 = 0.f, a3 = 0.f;
        for (int r = 0; r < R_REL; ++r) {
            int s  = rowptr[r * (N_NODES + 1) + grp];
            int e2 = rowptr[r * (N_NODES + 1) + grp + 1];
            const int* cr = colS + r * E_EDGES;
            int idx = s;
            for (; idx + 4 <= e2; idx += 4) {
                int c0 = cr[idx + 0], c1 = cr[idx + 1], c2 = cr[idx + 2], c3 = cr[idx + 3];
                a0 += S1p[c0 * 16 + c]; a1 += S1p[c1 * 16 + c];
                a2 += S1p[c2 * 16 + c]; a3 += S1p[c3 * 16 + c];
            }
            for (; idx < e2; ++idx) a0 += S1p[cr[idx] * 16 + c];
        }
        T[grp * C_CLS + c] = (a0 + a1) + (a2 + a3);
    }
}

// ---------------- K9: partial[b] = sum_{n in block} S1[n,k]*Tsum[n,c] ----------------
__global__ __launch_bounds__(256) void k_adjp_red(const float* __restrict__ S1, const float* __restrict__ T,
                                                  float* __restrict__ partial) {
    int t = threadIdx.x;
    if (t >= C_CLS * C_CLS) return;
    int k = t / C_CLS, c = t % C_CLS;
    int base = blockIdx.x * 64;
    float acc = 0.f;
    for (int i = 0; i < 64; ++i) {
        int n = base + i;
        acc += S1[n * C_CLS + k] * T[n * C_CLS + c];
    }
    partial[blockIdx.x * (C_CLS * C_CLS) + t] = acc;
}

// ---------------- K10: second cluster (tiny, one block) ----------------
__global__ void k_cluster2(const float* __restrict__ partialAdj, const float* __restrict__ xp,
                           const float* __restrict__ Ws2, float* __restrict__ out_x,
                           float* __restrict__ out_S2) {
    __shared__ float a2[C_CLS * C_CLS];
    __shared__ float xps[C_CLS * H_HID];
    __shared__ float y2[C_CLS * H_HID];
    __shared__ float lg[C_CLS * C_CLS];
    __shared__ float S2s[C_CLS * C_CLS];
    int t = threadIdx.x;   // 256 = H_HID
    if (t < C_CLS * C_CLS) {
        float s = 0.f;
        for (int b = 0; b < 128; ++b) s += partialAdj[b * (C_CLS * C_CLS) + t];
        a2[t] = s;
    }
    for (int i = t; i < C_CLS * H_HID; i += 256) xps[i] = xp[i];
    __syncthreads();
    for (int i = 0; i < C_CLS; ++i) {
        float acc = 0.f;
        #pragma unroll
        for (int j = 0; j < C_CLS; ++j) acc += a2[i * C_CLS + j] * xps[j * H_HID + t];
        y2[i * H_HID + t] = acc;
    }
    __syncthreads();
    for (int idx = t; idx < C_CLS * C_CLS; idx += 256) {
        int i = idx / C_CLS, c = idx % C_CLS;
        float acc = 0.f;
        for (int h = 0; h < H_HID; ++h) acc += y2[i * H_HID + h] * Ws2[h * C_CLS + c];
        lg[idx] = acc;
    }
    __syncthreads();
    if (t < C_CLS) {
        float m = -1e30f;
        for (int c = 0; c < C_CLS; ++c) m = fmaxf(m, lg[t * C_CLS + c]);
        float s = 0.f;
        for (int c = 0; c < C_CLS; ++c) { float ev = expf(lg[t * C_CLS + c] - m); S2s[t * C_CLS + c] = ev; s += ev; }
        for (int c = 0; c < C_CLS; ++c) { S2s[t * C_CLS + c] /= s; out_S2[t * C_CLS + c] = S2s[t * C_CLS + c]; }
    }
    __syncthreads();
    for (int c = 0; c < C_CLS; ++c) {
        float acc = 0.f;
        #pragma unroll
        for (int i = 0; i < C_CLS; ++i) acc += S2s[i * C_CLS + c] * xps[i * H_HID + t];
        out_x[c * H_HID + t] = acc;
    }
}

extern "C" void kernel_launch(void* const* d_in, const int* in_sizes, int n_in,
                              void* d_out, int out_size, void* d_ws, size_t ws_size,
                              hipStream_t stream) {
    const float* x_note  = (const float*)d_in[0];
    const int*   edges   = (const int*)d_in[1];
    const float* W_embed = (const float*)d_in[2];
    const float* b_embed = (const float*)d_in[3];
    const float* W_self  = (const float*)d_in[4];
    const float* W_neigh = (const float*)d_in[5];
    const float* b_gnn   = (const float*)d_in[6];
    const float* W_s1    = (const float*)d_in[7];
    const float* W_s2    = (const float*)d_in[8];
    float* out = (float*)d_out;

    // Output layout: x [15*256], S1 [8192*15], S2 [15*15]
    float* out_x  = out;
    float* out_S1 = out + C_CLS * H_HID;
    float* out_S2 = out + C_CLS * H_HID + N_NODES * C_CLS;

    // Region A (20MB), time-multiplexed:
    //   during k_prep:  hash [0:4MB)
    //   after:          colS [0:2MB) colD [2:4MB) H1 [4:12MB)
    //   overlay [12:20MB): G1 [12:12.5MB) S1p [12.5:13MB) xin [14:17MB)
    char* ws = (char*)d_ws;
    size_t off = 0;
    auto alloc = [&](size_t bytes) { size_t p = off; off += (bytes + 255) & ~(size_t)255; return p; };
    size_t regionA = alloc((size_t)20 * 1024 * 1024);
    size_t oDeg    = alloc((size_t)4 * N_NODES * 4);
    size_t oCur    = alloc((size_t)4 * N_NODES * 4);
    size_t oXp     = alloc((size_t)C_CLS * H_HID * 4);
    size_t zeroEnd = off;
    size_t oX0     = alloc((size_t)N_NODES * D_EMB * 4);
    size_t oRow    = alloc((size_t)4 * (N_NODES + 1) * 4);
    size_t oT      = alloc((size_t)N_NODES * C_CLS * 4);
    size_t oPart   = alloc((size_t)128 * C_CLS * C_CLS * 4);
    size_t oFlg    = alloc((size_t)(R_REL * E_EDGES) / 8);
    size_t oW96    = alloc((size_t)96 * H_HID * 4);

    unsigned int* hash = (unsigned int*)(ws + regionA);
    int*   colS   = (int*)(ws + regionA);
    int*   colD   = (int*)(ws + regionA + (size_t)2 * 1024 * 1024);
    float* H1     = (float*)(ws + regionA + (size_t)4 * 1024 * 1024);
    float* G1     = (float*)(ws + regionA + (size_t)12 * 1024 * 1024);
    float* S1p    = (float*)(ws + regionA + (size_t)12 * 1024 * 1024 + 512 * 1024);
    float* xin    = (float*)(ws + regionA + (size_t)14 * 1024 * 1024);
    int*   deg    = (int*)(ws + oDeg);
    int*   cur    = (int*)(ws + oCur);
    float* xp     = (float*)(ws + oXp);
    float* X0     = (float*)(ws + oX0);
    int*   rowptr = (int*)(ws + oRow);
    float* T      = (float*)(ws + oT);
    float* partialAdj = (float*)(ws + oPart);
    unsigned long long* flags64 = (unsigned long long*)(ws + oFlg);
    float* W96    = (float*)(ws + oW96);

    // zero hash table (4MB) + deg/cur/xp (~300KB)
    hipMemsetAsync(ws, 0, (size_t)R_REL * HCAP * 4, stream);
    hipMemsetAsync(ws + oDeg, 0, zeroEnd - oDeg, stream);

    k_prep<<<3168, 256, 0, stream>>>(x_note, W_embed, b_embed, X0, edges, deg, hash, flags64,
                                     W_self, W_neigh, W96);
    k_scan<<<4, 1024, 0, stream>>>(deg, rowptr);
    k_build<<<4096, 256, 0, stream>>>(edges, rowptr, flags64, cur, colD, colS);
    k_mean<<<(R_REL * N_NODES) / 8, 256, 0, stream>>>(X0, rowptr, colD, xin);
    k_gemm96<<<(N_NODES / 64) * (H_HID / 64), 256, 0, stream>>>(xin, W96, b_gnn, H1);
    k_g1<<<N_NODES / 16, 256, 0, stream>>>(H1, W_s1, G1);
    k_logits_sm<<<(N_NODES * 16) / 256, 256, 0, stream>>>(rowptr, colS, G1, out_S1, S1p);
    k_xpT<<<32 + 512, 256, 0, stream>>>(out_S1, H1, xp, rowptr, colS, S1p, T);
    k_adjp_red<<<128, 256, 0, stream>>>(out_S1, T, partialAdj);
    k_cluster2<<<1, 256, 0, stream>>>(partialAdj, xp, W_s2, out_x, out_S2);
}

// Round 9
// 219.785 us; speedup vs baseline: 1.1271x; 1.1271x over previous
//
#include <hip/hip_runtime.h>
#include <hip/hip_bf16.h>

#define N_NODES 8192
#define E_EDGES 262144
#define R_REL   2
#define F_FEAT  111
#define D_EMB   32
#define H_HID   256
#define C_CLS   15
#define DCAP    256               // max staged row length for dedup (Poisson(32) max ~80)

// ---------------- K1: fused prep: embed | dst-degree count | W96 concat ----------------
__global__ void k_prep(const float* __restrict__ x_note, const float* __restrict__ W,
                       const float* __restrict__ b, float* __restrict__ X0,
                       const int* __restrict__ edges, int* __restrict__ deg,
                       const float* __restrict__ Wself, const float* __restrict__ Wneigh,
                       float* __restrict__ W96) {
    int blk = blockIdx.x;
    if (blk < 1024) {
        __shared__ float Ws[F_FEAT * D_EMB];
        for (int i = threadIdx.x; i < F_FEAT * D_EMB; i += blockDim.x) Ws[i] = W[i];
        __syncthreads();
        int tid = blk * 256 + threadIdx.x;
        int n = tid >> 5, d = tid & 31;
        const float* xr = x_note + n * F_FEAT;
        float acc = b[d];
        for (int f = 0; f < F_FEAT; ++f) acc += xr[f] * Ws[f * D_EMB + d];
        X0[n * D_EMB + d] = acc;
    } else if (blk < 3072) {
        int i = (blk - 1024) * 256 + threadIdx.x;     // R*E edges
        int r = i >> 18, e = i & (E_EDGES - 1);
        int dst = edges[(r * 2 + 1) * E_EDGES + e];
        atomicAdd(&deg[(2 + r) * N_NODES + dst], 1);
    } else {
        int i = (blk - 3072) * 256 + threadIdx.x;     // 96*256
        int dd = i >> 8, h = i & 255;
        float v;
        if (dd < 32)      v = Wself[dd * 256 + h] + Wself[(32 + dd) * 256 + h];
        else if (dd < 64) v = Wneigh[(dd - 32) * 256 + h];
        else              v = Wneigh[(32 + dd - 64) * 256 + h];
        W96[i] = v;
    }
}

// ---------------- K2: exclusive scan of deg -> rowptr (one block per array) ----------------
__global__ void k_scan(const int* __restrict__ deg, int* __restrict__ rowptr) {
    int r = blockIdx.x;
    __shared__ int part[1024];
    int t = threadIdx.x;
    int base = t * 8;
    int local[8];
    int s = 0;
    #pragma unroll
    for (int i = 0; i < 8; ++i) { local[i] = s; s += deg[r * N_NODES + base + i]; }
    part[t] = s;
    __syncthreads();
    for (int off = 1; off < 1024; off <<= 1) {
        int v = (t >= off) ? part[t - off] : 0;
        __syncthreads();
        if (t >= off) part[t] += v;
        __syncthreads();
    }
    int pre = (t > 0) ? part[t - 1] : 0;
    #pragma unroll
    for (int i = 0; i < 8; ++i) rowptr[r * (N_NODES + 1) + base + i] = pre + local[i];
    if (t == 1023) rowptr[r * (N_NODES + 1) + N_NODES] = part[1023];
}

// ---------------- K3: dup dst-CSR scatter: colD[row=dst] = src ----------------
__global__ void k_build1(const int* __restrict__ edges, const int* __restrict__ rowptr,
                         int* __restrict__ cur, int* __restrict__ colD) {
    int i = blockIdx.x * blockDim.x + threadIdx.x;     // R*E edges
    int r = i >> 18, e = i & (E_EDGES - 1);
    int src = edges[(r * 2) * E_EDGES + e];
    int dst = edges[(r * 2 + 1) * E_EDGES + e];
    int posD = rowptr[(2 + r) * (N_NODES + 1) + dst] + atomicAdd(&cur[(2 + r) * N_NODES + dst], 1);
    colD[r * E_EDGES + posD] = src;
}

// ---------------- K4: wave-per-row dedup: flagsB[entry]=first-occurrence, count src-degree ----------------
__global__ __launch_bounds__(256) void k_dedup(const int* __restrict__ rowptr,
                                               const int* __restrict__ colD,
                                               int* __restrict__ deg,
                                               unsigned char* __restrict__ flagsB) {
    __shared__ int buf[4][DCAP];
    int w = threadIdx.x >> 6, lane = threadIdx.x & 63;
    int row = blockIdx.x * 4 + w;                      // 16384 (r,dst) rows
    int r = row >> 13, n = row & (N_NODES - 1);
    int s  = rowptr[(2 + r) * (N_NODES + 1) + n];
    int e2 = rowptr[(2 + r) * (N_NODES + 1) + n + 1];
    int len = e2 - s;
    const int* base = colD + r * E_EDGES + s;
    for (int i = lane; i < len && i < DCAP; i += 64) buf[w][i] = base[i];
    __syncthreads();
    for (int i = lane; i < len; i += 64) {
        int v = (i < DCAP) ? buf[w][i] : base[i];
        bool dup = false;
        int lim = (i < DCAP) ? i : DCAP;
        for (int j = 0; j < lim; ++j) if (buf[w][j] == v) { dup = true; break; }
        if (!dup && i >= DCAP)                       // safety fallback, never taken in practice
            for (int j = DCAP; j < i; ++j) if (base[j] == v) { dup = true; break; }
        flagsB[r * E_EDGES + s + i] = dup ? 0 : 1;
        if (!dup) atomicAdd(&deg[r * N_NODES + v], 1);
    }
}

// ---------------- K5: wave-per-row scatter of survivors into dedup src-CSR colS ----------------
__global__ __launch_bounds__(256) void k_buildS(const int* __restrict__ rowptr,
                                                const int* __restrict__ colD,
                                                const unsigned char* __restrict__ flagsB,
                                                int* __restrict__ cur, int* __restrict__ colS) {
    int w = threadIdx.x >> 6, lane = threadIdx.x & 63;
    int row = blockIdx.x * 4 + w;
    int r = row >> 13, n = row & (N_NODES - 1);
    int s  = rowptr[(2 + r) * (N_NODES + 1) + n];
    int e2 = rowptr[(2 + r) * (N_NODES + 1) + n + 1];
    for (int i = s + lane; i < e2; i += 64) {
        if (!flagsB[r * E_EDGES + i]) continue;
        int src = colD[r * E_EDGES + i];
        int posS = rowptr[r * (N_NODES + 1) + src] + atomicAdd(&cur[r * N_NODES + src], 1);
        colS[r * E_EDGES + posS] = n;
    }
}

// ---------------- K6: xin[n] = [X0[n] | mean_r0 | mean_r1]  (gather, unroll-4) ----------------
__global__ __launch_bounds__(256) void k_mean(const float* __restrict__ X0,
                                              const int* __restrict__ rowptr,
                                              const int* __restrict__ colD,
                                              float* __restrict__ xin) {
    int p = blockIdx.x * 8 + (threadIdx.x >> 5);   // (node, relation) pair, 16384 total
    int d = threadIdx.x & 31;
    int n = p >> 1, r = p & 1;
    int s  = rowptr[(2 + r) * (N_NODES + 1) + n];
    int e2 = rowptr[(2 + r) * (N_NODES + 1) + n + 1];
    const int* cr = colD + r * E_EDGES;
    float a0 = 0.f, a1 = 0.f, a2 = 0.f, a3 = 0.f;
    int idx = s;
    for (; idx + 4 <= e2; idx += 4) {
        int c0 = cr[idx], c1 = cr[idx + 1], c2 = cr[idx + 2], c3 = cr[idx + 3];
        a0 += X0[c0 * D_EMB + d]; a1 += X0[c1 * D_EMB + d];
        a2 += X0[c2 * D_EMB + d]; a3 += X0[c3 * D_EMB + d];
    }
    for (; idx < e2; ++idx) a0 += X0[cr[idx] * D_EMB + d];
    float inv = 1.f / fmaxf((float)(e2 - s), 1.f);
    xin[n * 96 + 32 + r * 32 + d] = ((a0 + a1) + (a2 + a3)) * inv;
    if (r == 0) xin[n * 96 + d] = X0[n * D_EMB + d];
}

// ---------------- K7: H1 = relu(xin @ W96 + b) — tiled GEMM 64x64x96 ----------------
__global__ __launch_bounds__(256) void k_gemm96(const float* __restrict__ xin,
                                                const float* __restrict__ W96,
                                                const float* __restrict__ bg,
                                                float* __restrict__ H1) {
    __shared__ float As[64][97];
    __shared__ float Bs[96][64];
    int bm = blockIdx.x >> 2, bn = blockIdx.x & 3;
    int t = threadIdx.x;
    int nb = bm * 64, cb = bn * 64;
    for (int i = t; i < 64 * 96; i += 256) { int row = i / 96, k = i - row * 96; As[row][k] = xin[(nb + row) * 96 + k]; }
    for (int i = t; i < 96 * 64; i += 256) { int k = i >> 6, col = i & 63; Bs[k][col] = W96[k * 256 + cb + col]; }
    __syncthreads();
    int tx = t & 15, ty = t >> 4;
    float acc[4][4] = {};
    #pragma unroll 4
    for (int k = 0; k < 96; ++k) {
        float a0 = As[ty * 4 + 0][k], a1 = As[ty * 4 + 1][k], a2 = As[ty * 4 + 2][k], a3 = As[ty * 4 + 3][k];
        float b0 = Bs[k][tx * 4 + 0], b1 = Bs[k][tx * 4 + 1], b2 = Bs[k][tx * 4 + 2], b3 = Bs[k][tx * 4 + 3];
        acc[0][0] += a0 * b0; acc[0][1] += a0 * b1; acc[0][2] += a0 * b2; acc[0][3] += a0 * b3;
        acc[1][0] += a1 * b0; acc[1][1] += a1 * b1; acc[1][2] += a1 * b2; acc[1][3] += a1 * b3;
        acc[2][0] += a2 * b0; acc[2][1] += a2 * b1; acc[2][2] += a2 * b2; acc[2][3] += a2 * b3;
        acc[3][0] += a3 * b0; acc[3][1] += a3 * b1; acc[3][2] += a3 * b2; acc[3][3] += a3 * b3;
    }
    #pragma unroll
    for (int i = 0; i < 4; ++i) {
        int n = nb + ty * 4 + i;
        #pragma unroll
        for (int j = 0; j < 4; ++j) {
            int c = cb + tx * 4 + j;
            H1[n * H_HID + c] = fmaxf(acc[i][j] + bg[c] + bg[H_HID + c], 0.f);
        }
    }
}

// ---------------- K8: G1 = H1 @ W_s1 (col 15 padded 0), LDS-staged ----------------
__global__ __launch_bounds__(256) void k_g1(const float* __restrict__ H1,
                                            const float* __restrict__ Ws,
                                            float* __restrict__ G1) {
    __shared__ float hl[16][H_HID + 1];
    __shared__ float Wlds[H_HID][16];
    int t = threadIdx.x;
    int nb = blockIdx.x * 16;
    #pragma unroll
    for (int c = 0; c < C_CLS; ++c) Wlds[t][c] = Ws[t * C_CLS + c];
    #pragma unroll
    for (int i = 0; i < 16; ++i) hl[i][t] = H1[(nb + i) * H_HID + t];
    __syncthreads();
    int g = t >> 4, c = t & 15;
    float acc = 0.f;
    if (c < C_CLS) {
        #pragma unroll 4
        for (int h = 0; h < H_HID; ++h) acc += hl[g][h] * Wlds[h][c];
    }
    G1[(nb + g) * 16 + c] = acc;
}

// ---------------- K9: logits via CSR gather of G1; softmax -> S1 + padded S1p ----------------
__global__ __launch_bounds__(256) void k_logits_sm(const int* __restrict__ rowptr,
                                                   const int* __restrict__ colS,
                                                   const float* __restrict__ G1,
                                                   float* __restrict__ S1,
                                                   float* __restrict__ S1p) {
    int n = (blockIdx.x * blockDim.x + threadIdx.x) >> 4;   // node
    int c = threadIdx.x & 15;
    float a0 = 0.f, a1 = 0.f, a2 = 0.f, a3 = 0.f;
    for (int r = 0; r < R_REL; ++r) {
        int s  = rowptr[r * (N_NODES + 1) + n];
        int e2 = rowptr[r * (N_NODES + 1) + n + 1];
        const int* cr = colS + r * E_EDGES;
        int idx = s;
        for (; idx + 4 <= e2; idx += 4) {
            int c0 = cr[idx + 0], c1 = cr[idx + 1], c2 = cr[idx + 2], c3 = cr[idx + 3];
            a0 += G1[c0 * 16 + c]; a1 += G1[c1 * 16 + c];
            a2 += G1[c2 * 16 + c]; a3 += G1[c3 * 16 + c];
        }
        for (; idx < e2; ++idx) a0 += G1[cr[idx] * 16 + c];
    }
    float logit = (c < C_CLS) ? ((a0 + a1) + (a2 + a3)) : -1e30f;
    float m = logit;
    for (int off = 8; off; off >>= 1) m = fmaxf(m, __shfl_xor(m, off, 16));
    float e = (c < C_CLS) ? expf(logit - m) : 0.f;
    float ssum = e;
    for (int off = 8; off; off >>= 1) ssum += __shfl_xor(ssum, off, 16);
    float p = e / ssum;
    if (c < C_CLS) S1[n * C_CLS + c] = p;
    S1p[n * 16 + c] = (c < C_CLS) ? p : 0.f;
}

// ---------------- K10: fused xp (blocks 0..31) | Tsum (blocks 32..543) ----------------
__global__ __launch_bounds__(256) void k_xpT(const float* __restrict__ S1, const float* __restrict__ H1,
                                             float* __restrict__ xp,
                                             const int* __restrict__ rowptr, const int* __restrict__ colS,
                                             const float* __restrict__ S1p, float* __restrict__ T) {
    int blk = blockIdx.x;
    if (blk < 32) {
        int h = threadIdx.x;
        int base = blk * 256;
        float acc[C_CLS];
        #pragma unroll
        for (int c = 0; c < C_CLS; ++c) acc[c] = 0.f;
        for (int i = 0; i < 256; ++i) {
            int n = base + i;
            float hv = H1[n * H_HID + h];
            const float* sr = S1 + n * C_CLS;
            #pragma unroll
            for (int c = 0; c < C_CLS; ++c) acc[c] += sr[c] * hv;
        }
        #pragma unroll
        for (int c = 0; c < C_CLS; ++c) atomicAdd(&xp[c * H_HID + h], acc[c]);
    } else {
        int grp = ((blk - 32) * 256 + threadIdx.x) >> 4;   // node
        int c = threadIdx.x & 15;
        if (c >= C_CLS) return;
        float a0 = 0.f, a1 = 0.f, a2 = 0.f, a3 = 0.f;
        for (int r = 0; r < R_REL; ++r) {
            int s  = rowptr[r * (N_NODES + 1) + grp];
            int e2 = rowptr[r * (N_NODES + 1) + grp + 1];
            const int* cr = colS + r * E_EDGES;
            int idx = s;
            for (; idx + 4 <= e2; idx += 4) {
                int c0 = cr[idx + 0], c1 = cr[idx + 1], c2 = cr[idx + 2], c3 = cr[idx + 3];
                a0 += S1p[c0 * 16 + c]; a1 += S1p[c1 * 16 + c];
                a2 += S1p[c2 * 16 + c]; a3 += S1p[c3 * 16 + c];
            }
            for (; idx < e2; ++idx) a0 += S1p[cr[idx] * 16 + c];
        }
        T[grp * C_CLS + c] = (a0 + a1) + (a2 + a3);
    }
}

// ---------------- K11: partial[b] = sum_{n in block} S1[n,k]*Tsum[n,c] ----------------
__global__ __launch_bounds__(256) void k_adjp_red(const float* __restrict__ S1, const float* __restrict__ T,
                                                  float* __restrict__ partial) {
    int t = threadIdx.x;
    if (t >= C_CLS * C_CLS) return;
    int k = t / C_CLS, c = t % C_CLS;
    int base = blockIdx.x * 64;
    float acc = 0.f;
    for (int i = 0; i < 64; ++i) {
        int n = base + i;
        acc += S1[n * C_CLS + k] * T[n * C_CLS + c];
    }
    partial[blockIdx.x * (C_CLS * C_CLS) + t] = acc;
}

// ---------------- K12: second cluster (tiny, one block) ----------------
__global__ void k_cluster2(const float* __restrict__ partialAdj, const float* __restrict__ xp,
                           const float* __restrict__ Ws2, float* __restrict__ out_x,
                           float* __restrict__ out_S2) {
    __shared__ float a2[C_CLS * C_CLS];
    __shared__ float xps[C_CLS * H_HID];
    __shared__ float y2[C_CLS * H_HID];
    __shared__ float lg[C_CLS * C_CLS];
    __shared__ float S2s[C_CLS * C_CLS];
    int t = threadIdx.x;   // 256 = H_HID
    if (t < C_CLS * C_CLS) {
        float s = 0.f;
        for (int b = 0; b < 128; ++b) s += partialAdj[b * (C_CLS * C_CLS) + t];
        a2[t] = s;
    }
    for (int i = t; i < C_CLS * H_HID; i += 256) xps[i] = xp[i];
    __syncthreads();
    for (int i = 0; i < C_CLS; ++i) {
        float acc = 0.f;
        #pragma unroll
        for (int j = 0; j < C_CLS; ++j) acc += a2[i * C_CLS + j] * xps[j * H_HID + t];
        y2[i * H_HID + t] = acc;
    }
    __syncthreads();
    for (int idx = t; idx < C_CLS * C_CLS; idx += 256) {
        int i = idx / C_CLS, c = idx % C_CLS;
        float acc = 0.f;
        for (int h = 0; h < H_HID; ++h) acc += y2[i * H_HID + h] * Ws2[h * C_CLS + c];
        lg[idx] = acc;
    }
    __syncthreads();
    if (t < C_CLS) {
        float m = -1e30f;
        for (int c = 0; c < C_CLS; ++c) m = fmaxf(m, lg[t * C_CLS + c]);
        float s = 0.f;
        for (int c = 0; c < C_CLS; ++c) { float ev = expf(lg[t * C_CLS + c] - m); S2s[t * C_CLS + c] = ev; s += ev; }
        for (int c = 0; c < C_CLS; ++c) { S2s[t * C_CLS + c] /= s; out_S2[t * C_CLS + c] = S2s[t * C_CLS + c]; }
    }
    __syncthreads();
    for (int c = 0; c < C_CLS; ++c) {
        float acc = 0.f;
        #pragma unroll
        for (int i = 0; i < C_CLS; ++i) acc += S2s[i * C_CLS + c] * xps[i * H_HID + t];
        out_x[c * H_HID + t] = acc;
    }
}

extern "C" void kernel_launch(void* const* d_in, const int* in_sizes, int n_in,
                              void* d_out, int out_size, void* d_ws, size_t ws_size,
                              hipStream_t stream) {
    const float* x_note  = (const float*)d_in[0];
    const int*   edges   = (const int*)d_in[1];
    const float* W_embed = (const float*)d_in[2];
    const float* b_embed = (const float*)d_in[3];
    const float* W_self  = (const float*)d_in[4];
    const float* W_neigh = (const float*)d_in[5];
    const float* b_gnn   = (const float*)d_in[6];
    const float* W_s1    = (const float*)d_in[7];
    const float* W_s2    = (const float*)d_in[8];
    float* out = (float*)d_out;

    float* out_x  = out;
    float* out_S1 = out + C_CLS * H_HID;
    float* out_S2 = out + C_CLS * H_HID + N_NODES * C_CLS;

    // Region A (20MB): colS [0:2MB) colD [2:4MB) H1 [4:12MB)
    //   overlay [12:20MB): G1 [12:12.5MB) S1p [12.5:13MB) xin [14:17MB)
    char* ws = (char*)d_ws;
    size_t off = 0;
    auto alloc = [&](size_t bytes) { size_t p = off; off += (bytes + 255) & ~(size_t)255; return p; };
    size_t regionA = alloc((size_t)20 * 1024 * 1024);
    size_t oDeg    = alloc((size_t)4 * N_NODES * 4);
    size_t oCur    = alloc((size_t)4 * N_NODES * 4);
    size_t oXp     = alloc((size_t)C_CLS * H_HID * 4);
    size_t zeroEnd = off;
    size_t oX0     = alloc((size_t)N_NODES * D_EMB * 4);
    size_t oRow    = alloc((size_t)4 * (N_NODES + 1) * 4);
    size_t oT      = alloc((size_t)N_NODES * C_CLS * 4);
    size_t oPart   = alloc((size_t)128 * C_CLS * C_CLS * 4);
    size_t oFlgB   = alloc((size_t)R_REL * E_EDGES);
    size_t oW96    = alloc((size_t)96 * H_HID * 4);

    int*   colS   = (int*)(ws + regionA);
    int*   colD   = (int*)(ws + regionA + (size_t)2 * 1024 * 1024);
    float* H1     = (float*)(ws + regionA + (size_t)4 * 1024 * 1024);
    float* G1     = (float*)(ws + regionA + (size_t)12 * 1024 * 1024);
    float* S1p    = (float*)(ws + regionA + (size_t)12 * 1024 * 1024 + 512 * 1024);
    float* xin    = (float*)(ws + regionA + (size_t)14 * 1024 * 1024);
    int*   deg    = (int*)(ws + oDeg);
    int*   cur    = (int*)(ws + oCur);
    float* xp     = (float*)(ws + oXp);
    float* X0     = (float*)(ws + oX0);
    int*   rowptr = (int*)(ws + oRow);
    float* T      = (float*)(ws + oT);
    float* partialAdj = (float*)(ws + oPart);
    unsigned char* flagsB = (unsigned char*)(ws + oFlgB);
    float* W96    = (float*)(ws + oW96);

    // zero only deg/cur/xp (~300 KB)
    hipMemsetAsync(ws + oDeg, 0, zeroEnd - oDeg, stream);

    k_prep<<<3168, 256, 0, stream>>>(x_note, W_embed, b_embed, X0, edges, deg, W_self, W_neigh, W96);
    k_scan<<<2, 1024, 0, stream>>>(deg + 2 * N_NODES, rowptr + 2 * (N_NODES + 1));   // dst arrays
    k_build1<<<(R_REL * E_EDGES) / 256, 256, 0, stream>>>(edges, rowptr, cur, colD);
    k_dedup<<<(R_REL * N_NODES) / 4, 256, 0, stream>>>(rowptr, colD, deg, flagsB);
    k_scan<<<2, 1024, 0, stream>>>(deg, rowptr);                                     // src arrays
    k_buildS<<<(R_REL * N_NODES) / 4, 256, 0, stream>>>(rowptr, colD, flagsB, cur, colS);
    k_mean<<<(R_REL * N_NODES) / 8, 256, 0, stream>>>(X0, rowptr, colD, xin);
    k_gemm96<<<(N_NODES / 64) * (H_HID / 64), 256, 0, stream>>>(xin, W96, b_gnn, H1);
    k_g1<<<N_NODES / 16, 256, 0, stream>>>(H1, W_s1, G1);
    k_logits_sm<<<(N_NODES * 16) / 256, 256, 0, stream>>>(rowptr, colS, G1, out_S1, S1p);
    k_xpT<<<32 + 512, 256, 0, stream>>>(out_S1, H1, xp, rowptr, colS, S1p, T);
    k_adjp_red<<<128, 256, 0, stream>>>(out_S1, T, partialAdj);
    k_cluster2<<<1, 256, 0, stream>>>(partialAdj, xp, W_s2, out_x, out_S2);
}

// Round 10
// 190.332 us; speedup vs baseline: 1.3016x; 1.1547x over previous
//
#include <hip/hip_runtime.h>
#include <hip/hip_bf16.h>

#define N_NODES 8192
#define E_EDGES 262144
#define R_REL   2
#define F_FEAT  111
#define D_EMB   32
#define H_HID   256
#define C_CLS   15
#define DCAP    256               // max staged row length for dedup (Poisson(32) max ~80)

// ---------------- K1: fused prep: embed | dst-degree count | W96 concat ----------------
__global__ void k_prep(const float* __restrict__ x_note, const float* __restrict__ W,
                       const float* __restrict__ b, float* __restrict__ X0,
                       const int* __restrict__ edges, int* __restrict__ deg,
                       const float* __restrict__ Wself, const float* __restrict__ Wneigh,
                       float* __restrict__ W96) {
    int blk = blockIdx.x;
    if (blk < 1024) {
        __shared__ float Ws[F_FEAT * D_EMB];
        for (int i = threadIdx.x; i < F_FEAT * D_EMB; i += blockDim.x) Ws[i] = W[i];
        __syncthreads();
        int tid = blk * 256 + threadIdx.x;
        int n = tid >> 5, d = tid & 31;
        const float* xr = x_note + n * F_FEAT;
        float acc = b[d];
        for (int f = 0; f < F_FEAT; ++f) acc += xr[f] * Ws[f * D_EMB + d];
        X0[n * D_EMB + d] = acc;
    } else if (blk < 3072) {
        int i = (blk - 1024) * 256 + threadIdx.x;     // R*E edges
        int r = i >> 18, e = i & (E_EDGES - 1);
        int dst = edges[(r * 2 + 1) * E_EDGES + e];
        atomicAdd(&deg[(2 + r) * N_NODES + dst], 1);
    } else {
        int i = (blk - 3072) * 256 + threadIdx.x;     // 96*256
        int dd = i >> 8, h = i & 255;
        float v;
        if (dd < 32)      v = Wself[dd * 256 + h] + Wself[(32 + dd) * 256 + h];
        else if (dd < 64) v = Wneigh[(dd - 32) * 256 + h];
        else              v = Wneigh[(32 + dd - 64) * 256 + h];
        W96[i] = v;
    }
}

// ---------------- K2: exclusive scan of deg -> rowptr (one block per array) ----------------
__global__ void k_scan(const int* __restrict__ deg, int* __restrict__ rowptr) {
    int r = blockIdx.x;
    __shared__ int part[1024];
    int t = threadIdx.x;
    int base = t * 8;
    int local[8];
    int s = 0;
    #pragma unroll
    for (int i = 0; i < 8; ++i) { local[i] = s; s += deg[r * N_NODES + base + i]; }
    part[t] = s;
    __syncthreads();
    for (int off = 1; off < 1024; off <<= 1) {
        int v = (t >= off) ? part[t - off] : 0;
        __syncthreads();
        if (t >= off) part[t] += v;
        __syncthreads();
    }
    int pre = (t > 0) ? part[t - 1] : 0;
    #pragma unroll
    for (int i = 0; i < 8; ++i) rowptr[r * (N_NODES + 1) + base + i] = pre + local[i];
    if (t == 1023) rowptr[r * (N_NODES + 1) + N_NODES] = part[1023];
}

// ---------------- K3: dup dst-CSR scatter: colD[row=dst] = src ----------------
__global__ void k_build1(const int* __restrict__ edges, const int* __restrict__ rowptr,
                         int* __restrict__ cur, int* __restrict__ colD) {
    int i = blockIdx.x * blockDim.x + threadIdx.x;     // R*E edges
    int r = i >> 18, e = i & (E_EDGES - 1);
    int src = edges[(r * 2) * E_EDGES + e];
    int dst = edges[(r * 2 + 1) * E_EDGES + e];
    int posD = rowptr[(2 + r) * (N_NODES + 1) + dst] + atomicAdd(&cur[(2 + r) * N_NODES + dst], 1);
    colD[r * E_EDGES + posD] = src;
}

// ---------------- K4: fused: [0,4096) wave-per-row dedup | [4096,6144) mean gather ----------------
__global__ __launch_bounds__(256) void k_dedup_mean(const int* __restrict__ rowptr,
                                                    const int* __restrict__ colD,
                                                    int* __restrict__ deg,
                                                    unsigned char* __restrict__ flagsB,
                                                    const float* __restrict__ X0,
                                                    float* __restrict__ xin) {
    int blk = blockIdx.x;
    if (blk < 4096) {
        __shared__ int buf[4][DCAP];
        int w = threadIdx.x >> 6, lane = threadIdx.x & 63;
        int row = blk * 4 + w;                         // 16384 (r,dst) rows
        int r = row >> 13, n = row & (N_NODES - 1);
        int s  = rowptr[(2 + r) * (N_NODES + 1) + n];
        int e2 = rowptr[(2 + r) * (N_NODES + 1) + n + 1];
        int len = e2 - s;
        const int* base = colD + r * E_EDGES + s;
        for (int i = lane; i < len && i < DCAP; i += 64) buf[w][i] = base[i];
        __syncthreads();
        for (int i = lane; i < len; i += 64) {
            int v = (i < DCAP) ? buf[w][i] : base[i];
            bool dup = false;
            int lim = (i < DCAP) ? i : DCAP;
            for (int j = 0; j < lim; ++j) if (buf[w][j] == v) { dup = true; break; }
            if (!dup && i >= DCAP)
                for (int j = DCAP; j < i; ++j) if (base[j] == v) { dup = true; break; }
            flagsB[r * E_EDGES + s + i] = dup ? 0 : 1;
            if (!dup) atomicAdd(&deg[r * N_NODES + v], 1);
        }
    } else {
        int p = (blk - 4096) * 8 + (threadIdx.x >> 5); // (node, relation) pair, 16384
        int d = threadIdx.x & 31;
        int n = p >> 1, r = p & 1;
        int s  = rowptr[(2 + r) * (N_NODES + 1) + n];
        int e2 = rowptr[(2 + r) * (N_NODES + 1) + n + 1];
        const int* cr = colD + r * E_EDGES;
        float a0 = 0.f, a1 = 0.f, a2 = 0.f, a3 = 0.f;
        int idx = s;
        for (; idx + 4 <= e2; idx += 4) {
            int c0 = cr[idx], c1 = cr[idx + 1], c2 = cr[idx + 2], c3 = cr[idx + 3];
            a0 += X0[c0 * D_EMB + d]; a1 += X0[c1 * D_EMB + d];
            a2 += X0[c2 * D_EMB + d]; a3 += X0[c3 * D_EMB + d];
        }
        for (; idx < e2; ++idx) a0 += X0[cr[idx] * D_EMB + d];
        float inv = 1.f / fmaxf((float)(e2 - s), 1.f);
        xin[n * 96 + 32 + r * 32 + d] = ((a0 + a1) + (a2 + a3)) * inv;
        if (r == 0) xin[n * 96 + d] = X0[n * D_EMB + d];
    }
}

// ---------------- K5: fused: [0,4096) buildS scatter | [4096,4608) GEMM 64x64x96 ----------------
__global__ __launch_bounds__(256) void k_buildS_gemm(const int* __restrict__ rowptr,
                                                     const int* __restrict__ colD,
                                                     const unsigned char* __restrict__ flagsB,
                                                     int* __restrict__ cur, int* __restrict__ colS,
                                                     const float* __restrict__ xin,
                                                     const float* __restrict__ W96,
                                                     const float* __restrict__ bg,
                                                     float* __restrict__ H1) {
    __shared__ float As[64][97];
    __shared__ float Bs[96][64];
    int blk = blockIdx.x;
    if (blk < 4096) {
        int w = threadIdx.x >> 6, lane = threadIdx.x & 63;
        int row = blk * 4 + w;
        int r = row >> 13, n = row & (N_NODES - 1);
        int s  = rowptr[(2 + r) * (N_NODES + 1) + n];
        int e2 = rowptr[(2 + r) * (N_NODES + 1) + n + 1];
        for (int i = s + lane; i < e2; i += 64) {
            if (!flagsB[r * E_EDGES + i]) continue;
            int src = colD[r * E_EDGES + i];
            int posS = rowptr[r * (N_NODES + 1) + src] + atomicAdd(&cur[r * N_NODES + src], 1);
            colS[r * E_EDGES + posS] = n;
        }
    } else {
        int g = blk - 4096;
        int bm = g >> 2, bn = g & 3;
        int t = threadIdx.x;
        int nb = bm * 64, cb = bn * 64;
        for (int i = t; i < 64 * 96; i += 256) { int row = i / 96, k = i - row * 96; As[row][k] = xin[(nb + row) * 96 + k]; }
        for (int i = t; i < 96 * 64; i += 256) { int k = i >> 6, col = i & 63; Bs[k][col] = W96[k * 256 + cb + col]; }
        __syncthreads();
        int tx = t & 15, ty = t >> 4;
        float acc[4][4] = {};
        #pragma unroll 4
        for (int k = 0; k < 96; ++k) {
            float a0 = As[ty * 4 + 0][k], a1 = As[ty * 4 + 1][k], a2 = As[ty * 4 + 2][k], a3 = As[ty * 4 + 3][k];
            float b0 = Bs[k][tx * 4 + 0], b1 = Bs[k][tx * 4 + 1], b2 = Bs[k][tx * 4 + 2], b3 = Bs[k][tx * 4 + 3];
            acc[0][0] += a0 * b0; acc[0][1] += a0 * b1; acc[0][2] += a0 * b2; acc[0][3] += a0 * b3;
            acc[1][0] += a1 * b0; acc[1][1] += a1 * b1; acc[1][2] += a1 * b2; acc[1][3] += a1 * b3;
            acc[2][0] += a2 * b0; acc[2][1] += a2 * b1; acc[2][2] += a2 * b2; acc[2][3] += a2 * b3;
            acc[3][0] += a3 * b0; acc[3][1] += a3 * b1; acc[3][2] += a3 * b2; acc[3][3] += a3 * b3;
        }
        #pragma unroll
        for (int i = 0; i < 4; ++i) {
            int n = nb + ty * 4 + i;
            #pragma unroll
            for (int j = 0; j < 4; ++j) {
                int c = cb + tx * 4 + j;
                H1[n * H_HID + c] = fmaxf(acc[i][j] + bg[c] + bg[H_HID + c], 0.f);
            }
        }
    }
}

// ---------------- K6: G1 = H1 @ W_s1 (col 15 padded 0), LDS-staged ----------------
__global__ __launch_bounds__(256) void k_g1(const float* __restrict__ H1,
                                            const float* __restrict__ Ws,
                                            float* __restrict__ G1) {
    __shared__ float hl[16][H_HID + 1];
    __shared__ float Wlds[H_HID][16];
    int t = threadIdx.x;
    int nb = blockIdx.x * 16;
    #pragma unroll
    for (int c = 0; c < C_CLS; ++c) Wlds[t][c] = Ws[t * C_CLS + c];
    #pragma unroll
    for (int i = 0; i < 16; ++i) hl[i][t] = H1[(nb + i) * H_HID + t];
    __syncthreads();
    int g = t >> 4, c = t & 15;
    float acc = 0.f;
    if (c < C_CLS) {
        #pragma unroll 4
        for (int h = 0; h < H_HID; ++h) acc += hl[g][h] * Wlds[h][c];
    }
    G1[(nb + g) * 16 + c] = acc;
}

// ---------------- K7: logits via CSR gather of G1; softmax -> S1 + padded S1p ----------------
__global__ __launch_bounds__(256) void k_logits_sm(const int* __restrict__ rowptr,
                                                   const int* __restrict__ colS,
                                                   const float* __restrict__ G1,
                                                   float* __restrict__ S1,
                                                   float* __restrict__ S1p) {
    int n = (blockIdx.x * blockDim.x + threadIdx.x) >> 4;   // node
    int c = threadIdx.x & 15;
    float a0 = 0.f, a1 = 0.f, a2 = 0.f, a3 = 0.f;
    for (int r = 0; r < R_REL; ++r) {
        int s  = rowptr[r * (N_NODES + 1) + n];
        int e2 = rowptr[r * (N_NODES + 1) + n + 1];
        const int* cr = colS + r * E_EDGES;
        int idx = s;
        for (; idx + 4 <= e2; idx += 4) {
            int c0 = cr[idx + 0], c1 = cr[idx + 1], c2 = cr[idx + 2], c3 = cr[idx + 3];
            a0 += G1[c0 * 16 + c]; a1 += G1[c1 * 16 + c];
            a2 += G1[c2 * 16 + c]; a3 += G1[c3 * 16 + c];
        }
        for (; idx < e2; ++idx) a0 += G1[cr[idx] * 16 + c];
    }
    float logit = (c < C_CLS) ? ((a0 + a1) + (a2 + a3)) : -1e30f;
    float m = logit;
    for (int off = 8; off; off >>= 1) m = fmaxf(m, __shfl_xor(m, off, 16));
    float e = (c < C_CLS) ? expf(logit - m) : 0.f;
    float ssum = e;
    for (int off = 8; off; off >>= 1) ssum += __shfl_xor(ssum, off, 16);
    float p = e / ssum;
    if (c < C_CLS) S1[n * C_CLS + c] = p;
    S1p[n * 16 + c] = (c < C_CLS) ? p : 0.f;
}

// ---------------- K8: fused xp (blocks 0..127, 64 nodes each) | Tsum (blocks 128..639) ----------------
__global__ __launch_bounds__(256) void k_xpT(const float* __restrict__ S1, const float* __restrict__ H1,
                                             float* __restrict__ xp,
                                             const int* __restrict__ rowptr, const int* __restrict__ colS,
                                             const float* __restrict__ S1p, float* __restrict__ T) {
    int blk = blockIdx.x;
    if (blk < 128) {
        int h = threadIdx.x;
        int base = blk * 64;
        float acc[C_CLS];
        #pragma unroll
        for (int c = 0; c < C_CLS; ++c) acc[c] = 0.f;
        for (int i = 0; i < 64; ++i) {
            int n = base + i;
            float hv = H1[n * H_HID + h];
            const float* sr = S1 + n * C_CLS;
            #pragma unroll
            for (int c = 0; c < C_CLS; ++c) acc[c] += sr[c] * hv;
        }
        #pragma unroll
        for (int c = 0; c < C_CLS; ++c) atomicAdd(&xp[c * H_HID + h], acc[c]);
    } else {
        int grp = ((blk - 128) * 256 + threadIdx.x) >> 4;   // node
        int c = threadIdx.x & 15;
        if (c >= C_CLS) return;
        float a0 = 0.f, a1 = 0.f, a2 = 0.f, a3 = 0.f;
        for (int r = 0; r < R_REL; ++r) {
            int s  = rowptr[r * (N_NODES + 1) + grp];
            int e2 = rowptr[r * (N_NODES + 1) + grp + 1];
            const int* cr = colS + r * E_EDGES;
            int idx = s;
            for (; idx + 4 <= e2; idx += 4) {
                int c0 = cr[idx + 0], c1 = cr[idx + 1], c2 = cr[idx + 2], c3 = cr[idx + 3];
                a0 += S1p[c0 * 16 + c]; a1 += S1p[c1 * 16 + c];
                a2 += S1p[c2 * 16 + c]; a3 += S1p[c3 * 16 + c];
            }
            for (; idx < e2; ++idx) a0 += S1p[cr[idx] * 16 + c];
        }
        T[grp * C_CLS + c] = (a0 + a1) + (a2 + a3);
    }
}

// ---------------- K9: partial[b] = sum_{n in block} S1[n,k]*Tsum[n,c] ----------------
__global__ __launch_bounds__(256) void k_adjp_red(const float* __restrict__ S1, const float* __restrict__ T,
                                                  float* __restrict__ partial) {
    int t = threadIdx.x;
    if (t >= C_CLS * C_CLS) return;
    int k = t / C_CLS, c = t % C_CLS;
    int base = blockIdx.x * 64;
    float acc = 0.f;
    for (int i = 0; i < 64; ++i) {
        int n = base + i;
        acc += S1[n * C_CLS + k] * T[n * C_CLS + c];
    }
    partial[blockIdx.x * (C_CLS * C_CLS) + t] = acc;
}

// ---------------- K10: second cluster (tiny, one block) ----------------
__global__ void k_cluster2(const float* __restrict__ partialAdj, const float* __restrict__ xp,
                           const float* __restrict__ Ws2, float* __restrict__ out_x,
                           float* __restrict__ out_S2) {
    __shared__ float a2[C_CLS * C_CLS];
    __shared__ float xps[C_CLS * H_HID];
    __shared__ float y2[C_CLS * H_HID];
    __shared__ float lg[C_CLS * C_CLS];
    __shared__ float S2s[C_CLS * C_CLS];
    int t = threadIdx.x;   // 256 = H_HID
    if (t < C_CLS * C_CLS) {
        float s = 0.f;
        for (int b = 0; b < 128; ++b) s += partialAdj[b * (C_CLS * C_CLS) + t];
        a2[t] = s;
    }
    for (int i = t; i < C_CLS * H_HID; i += 256) xps[i] = xp[i];
    __syncthreads();
    for (int i = 0; i < C_CLS; ++i) {
        float acc = 0.f;
        #pragma unroll
        for (int j = 0; j < C_CLS; ++j) acc += a2[i * C_CLS + j] * xps[j * H_HID + t];
        y2[i * H_HID + t] = acc;
    }
    __syncthreads();
    for (int idx = t; idx < C_CLS * C_CLS; idx += 256) {
        int i = idx / C_CLS, c = idx % C_CLS;
        float acc = 0.f;
        for (int h = 0; h < H_HID; ++h) acc += y2[i * H_HID + h] * Ws2[h * C_CLS + c];
        lg[idx] = acc;
    }
    __syncthreads();
    if (t < C_CLS) {
        float m = -1e30f;
        for (int c = 0; c < C_CLS; ++c) m = fmaxf(m, lg[t * C_CLS + c]);
        float s = 0.f;
        for (int c = 0; c < C_CLS; ++c) { float ev = expf(lg[t * C_CLS + c] - m); S2s[t * C_CLS + c] = ev; s += ev; }
        for (int c = 0; c < C_CLS; ++c) { S2s[t * C_CLS + c] /= s; out_S2[t * C_CLS + c] = S2s[t * C_CLS + c]; }
    }
    __syncthreads();
    for (int c = 0; c < C_CLS; ++c) {
        float acc = 0.f;
        #pragma unroll
        for (int i = 0; i < C_CLS; ++i) acc += S2s[i * C_CLS + c] * xps[i * H_HID + t];
        out_x[c * H_HID + t] = acc;
    }
}

extern "C" void kernel_launch(void* const* d_in, const int* in_sizes, int n_in,
                              void* d_out, int out_size, void* d_ws, size_t ws_size,
                              hipStream_t stream) {
    const float* x_note  = (const float*)d_in[0];
    const int*   edges   = (const int*)d_in[1];
    const float* W_embed = (const float*)d_in[2];
    const float* b_embed = (const float*)d_in[3];
    const float* W_self  = (const float*)d_in[4];
    const float* W_neigh = (const float*)d_in[5];
    const float* b_gnn   = (const float*)d_in[6];
    const float* W_s1    = (const float*)d_in[7];
    const float* W_s2    = (const float*)d_in[8];
    float* out = (float*)d_out;

    float* out_x  = out;
    float* out_S1 = out + C_CLS * H_HID;
    float* out_S2 = out + C_CLS * H_HID + N_NODES * C_CLS;

    // Region A (20MB): colS [0:2MB) colD [2:4MB) H1 [4:12MB)
    //   overlay [12:20MB): G1 [12:12.5MB) S1p [12.5:13MB) xin [14:17MB)
    char* ws = (char*)d_ws;
    size_t off = 0;
    auto alloc = [&](size_t bytes) { size_t p = off; off += (bytes + 255) & ~(size_t)255; return p; };
    size_t regionA = alloc((size_t)20 * 1024 * 1024);
    size_t oDeg    = alloc((size_t)4 * N_NODES * 4);
    size_t oCur    = alloc((size_t)4 * N_NODES * 4);
    size_t oXp     = alloc((size_t)C_CLS * H_HID * 4);
    size_t zeroEnd = off;
    size_t oX0     = alloc((size_t)N_NODES * D_EMB * 4);
    size_t oRow    = alloc((size_t)4 * (N_NODES + 1) * 4);
    size_t oT      = alloc((size_t)N_NODES * C_CLS * 4);
    size_t oPart   = alloc((size_t)128 * C_CLS * C_CLS * 4);
    size_t oFlgB   = alloc((size_t)R_REL * E_EDGES);
    size_t oW96    = alloc((size_t)96 * H_HID * 4);

    int*   colS   = (int*)(ws + regionA);
    int*   colD   = (int*)(ws + regionA + (size_t)2 * 1024 * 1024);
    float* H1     = (float*)(ws + regionA + (size_t)4 * 1024 * 1024);
    float* G1     = (float*)(ws + regionA + (size_t)12 * 1024 * 1024);
    float* S1p    = (float*)(ws + regionA + (size_t)12 * 1024 * 1024 + 512 * 1024);
    float* xin    = (float*)(ws + regionA + (size_t)14 * 1024 * 1024);
    int*   deg    = (int*)(ws + oDeg);
    int*   cur    = (int*)(ws + oCur);
    float* xp     = (float*)(ws + oXp);
    float* X0     = (float*)(ws + oX0);
    int*   rowptr = (int*)(ws + oRow);
    float* T      = (float*)(ws + oT);
    float* partialAdj = (float*)(ws + oPart);
    unsigned char* flagsB = (unsigned char*)(ws + oFlgB);
    float* W96    = (float*)(ws + oW96);

    // zero only deg/cur/xp (~300 KB)
    hipMemsetAsync(ws + oDeg, 0, zeroEnd - oDeg, stream);

    k_prep<<<3168, 256, 0, stream>>>(x_note, W_embed, b_embed, X0, edges, deg, W_self, W_neigh, W96);
    k_scan<<<2, 1024, 0, stream>>>(deg + 2 * N_NODES, rowptr + 2 * (N_NODES + 1));   // dst arrays
    k_build1<<<(R_REL * E_EDGES) / 256, 256, 0, stream>>>(edges, rowptr, cur, colD);
    k_dedup_mean<<<4096 + 2048, 256, 0, stream>>>(rowptr, colD, deg, flagsB, X0, xin);
    k_scan<<<2, 1024, 0, stream>>>(deg, rowptr);                                     // src arrays
    k_buildS_gemm<<<4096 + 512, 256, 0, stream>>>(rowptr, colD, flagsB, cur, colS,
                                                  xin, W96, b_gnn, H1);
    k_g1<<<N_NODES / 16, 256, 0, stream>>>(H1, W_s1, G1);
    k_logits_sm<<<(N_NODES * 16) / 256, 256, 0, stream>>>(rowptr, colS, G1, out_S1, S1p);
    k_xpT<<<128 + 512, 256, 0, stream>>>(out_S1, H1, xp, rowptr, colS, S1p, T);
    k_adjp_red<<<128, 256, 0, stream>>>(out_S1, T, partialAdj);
    k_cluster2<<<1, 256, 0, stream>>>(partialAdj, xp, W_s2, out_x, out_S2);
}